// Round 19
// baseline (309.295 us; speedup 1.0000x reference)
//
#include <hip/hip_runtime.h>

#define T 3
#define E 500000
#define F 128
#define H 64
#define B 1024

#define BLK_E 128
#define EMASK 0x7FFFF  // e < 2^19; graph packed in bits 19..28
#define PBX 512        // k_fused blocks per type

typedef __attribute__((ext_vector_type(4))) float f32x4;
typedef __fp16 h2 __attribute__((ext_vector_type(2)));
typedef __fp16 h8 __attribute__((ext_vector_type(8)));
union H4 {
  h2 p[2];
  uint2 d;
};
union HS {
  __fp16 h;
  unsigned short s;
};

// ---- helpers ----------------------------------------------------------

__device__ __forceinline__ float tanh_fast(float x) {
  float e = __expf(2.0f * x);
  return 1.0f - 2.0f / (e + 1.0f);
}
// LDS-only barrier: waits DS ops, leaves VMEM counters undrained (keeps
// next-tile gathers in flight). sched_barrier fences compiler motion.
__device__ __forceinline__ void bar_lds() {
  asm volatile("s_waitcnt lgkmcnt(0)" ::: "memory");
  __builtin_amdgcn_s_barrier();
  __builtin_amdgcn_sched_barrier(0);
}

// ---- kernel 0: zero accumulators + pack W1 (fp16 RNE) into B-frags ----
// Wpack[t][nt(4)][ks(4)][lane(64)][8]: lane l holds B-frag col j =
// nt*16+(l&15), k = ks*32+(l>>4)*8 + 0..7. W-lo not needed: neglected
// x*(w-wh) term ~1e-4 in score space (validated r15/r16: absmax 9.8e-4).

__global__ void k_init(const float* __restrict__ W1, float* __restrict__ acc,
                       float* __restrict__ ssum, unsigned* __restrict__ cnt,
                       unsigned short* __restrict__ Wpack) {
  int idx = blockIdx.x * blockDim.x + threadIdx.x;
  if (idx < T * B * F) acc[idx] = 0.0f;
  if (idx < T * B) {
    ssum[idx] = 0.0f;
    cnt[idx] = 0u;
  }
  if (idx < T * 4 * 4 * 64) {
    int lane = idx & 63;
    int r2 = idx >> 6;
    int ks = r2 & 3;
    int nt = (r2 >> 2) & 3;
    int t = r2 >> 4;
    int j = nt * 16 + (lane & 15);
#pragma unroll
    for (int e = 0; e < 8; ++e) {
      int f = ks * 32 + (lane >> 4) * 8 + e;
      HS hs;
      hs.h = (__fp16)W1[((size_t)t * F + f) * H + j];  // RNE
      Wpack[(size_t)idx * 8 + e] = hs.s;
    }
  }
}

// ---- kernel 1: LDS-local histogram (16384 edges/block) ----------------

__global__ __launch_bounds__(256) void k_hist(
    const int* __restrict__ batch, unsigned* __restrict__ cnt) {
  __shared__ unsigned h[B];
  int t = blockIdx.y;
  for (int i = threadIdx.x; i < B; i += 256) h[i] = 0u;
  __syncthreads();
  int base = blockIdx.x * 16384;
  int end = base + 16384 < E ? base + 16384 : E;
  for (int i = base + threadIdx.x; i < end; i += 256)
    atomicAdd(&h[batch[(size_t)t * E + i]], 1u);
  __syncthreads();
  for (int i = threadIdx.x; i < B; i += 256) {
    unsigned v = h[i];
    if (v) atomicAdd(&cnt[t * B + i], v);
  }
}

// ---- kernel 2: prefix sums — wave-shuffle scan (2 barriers) -----------

__global__ void k_scan(const unsigned* __restrict__ cnt,
                       unsigned* __restrict__ cursor) {
  __shared__ unsigned wsum[16];
  int tid = threadIdx.x;
  int t = blockIdx.x;
  unsigned v = cnt[t * B + tid];
  unsigned x = v;  // inclusive scan within the 64-lane wave
#pragma unroll
  for (int d = 1; d < 64; d <<= 1) {
    unsigned y = __shfl_up(x, d);
    if ((tid & 63) >= d) x += y;
  }
  if ((tid & 63) == 63) wsum[tid >> 6] = x;
  __syncthreads();
  if (tid < 16) {
    unsigned s = wsum[tid];
#pragma unroll
    for (int d = 1; d < 16; d <<= 1) {
      unsigned y = __shfl_up(s, d);
      if (tid >= d) s += y;
    }
    wsum[tid] = s;
  }
  __syncthreads();
  unsigned base = (tid >> 6) ? wsum[(tid >> 6) - 1] : 0u;
  cursor[t * B + tid] = base + x - v;  // exclusive
}

// ---- kernel 3: counting-sort scatter, 1024 edges/block ----------------

__global__ __launch_bounds__(256) void k_scatter(
    const int* __restrict__ batch, unsigned* __restrict__ cursor,
    unsigned* __restrict__ eid) {
  __shared__ unsigned hloc[B];
  __shared__ unsigned baseg[B];
  int t = blockIdx.y;
  int base = blockIdx.x * 1024;
  for (int i = threadIdx.x; i < B; i += 256) hloc[i] = 0u;
  __syncthreads();
  int bb[4];
  unsigned rk[4];
#pragma unroll
  for (int k = 0; k < 4; ++k) {
    int e = base + k * 256 + threadIdx.x;
    if (e < E) {
      bb[k] = batch[(size_t)t * E + e];
      rk[k] = atomicAdd(&hloc[bb[k]], 1u);
    }
  }
  __syncthreads();
  for (int i = threadIdx.x; i < B; i += 256) {
    unsigned cv = hloc[i];
    if (cv) baseg[i] = atomicAdd(&cursor[t * B + i], cv);
  }
  __syncthreads();
#pragma unroll
  for (int k = 0; k < 4; ++k) {
    int e = base + k * 256 + threadIdx.x;
    if (e < E)
      eid[(size_t)t * E + baseg[bb[k]] + rk[k]] =
          (unsigned)e | ((unsigned)bb[k] << 19);
  }
}

// ---- kernel 4: pipelined MFMA fused score + exp + scatter -------------
// r16 core scaled to BLK_E=128 / 512 threads (8 waves): per-edge barrier +
// epilogue overhead halves; in-flight gather 96->128 KB/CU. j-SPLIT waves:
// wave w = (rw=w&3 row-group of 32, jh=w>>2 j-half) holds only bh[2][4]
// (32 VGPR) -> peak ~118 VGPR, fits __launch_bounds__(512,4) cap 128.
// j-halves combine via scl2[2][128] at exp time. fp16 2-pass precision.

__global__ __launch_bounds__(512, 4) void k_fused(
    const float* __restrict__ ea, const unsigned* __restrict__ eid,
    const unsigned short* __restrict__ Wpack, const float* __restrict__ b1,
    const float* __restrict__ W2, const float* __restrict__ b2,
    float* __restrict__ accg, float* __restrict__ ssum) {
  __shared__ unsigned short xh_t[BLK_E * F];  // 32 KB fp16, row-swizzled
  __shared__ unsigned short xl_t[BLK_E * F];  // 32 KB fp16
  __shared__ float scl2[2][BLK_E];
  __shared__ int eidl[3][BLK_E];
  __shared__ int bblb[3][BLK_E];

  int t = blockIdx.y;
  int tid = threadIdx.x;
  const int NT = (E + BLK_E - 1) / BLK_E;
  const int CH = (NT + PBX - 1) / PBX;
  int t0 = blockIdx.x * CH;
  int n = NT - t0;
  if (n <= 0) return;
  if (n > CH) n = CH;

  const float* eag = ea + (size_t)t * E * (size_t)F;
  const unsigned* eidt = eid + (size_t)t * E;
  int l = tid & 63;
  int w = tid >> 6;   // 8 waves
  int rw = w & 3;     // row-group: rows rw*32 .. rw*32+31
  int jh = w >> 2;    // j-half: nt = jh*2 + {0,1}
  int c = tid & 31;
  int r0 = tid >> 5;  // 0..15
  int jb = l & 15;

  // ---- persistent B-fragments (half: 32 VGPRs) + epilogue constants ----
  const unsigned short* wpt = Wpack + (size_t)t * 8192;
  h8 bh[2][4];
#pragma unroll
  for (int n2 = 0; n2 < 2; ++n2)
#pragma unroll
    for (int ks = 0; ks < 4; ++ks)
      bh[n2][ks] = *(const h8*)(wpt + (((jh * 2 + n2) * 4 + ks) * 64 + l) * 8);
  float b1r[2], w2r[2];
#pragma unroll
  for (int n2 = 0; n2 < 2; ++n2) {
    b1r[n2] = b1[t * H + (jh * 2 + n2) * 16 + jb];
    w2r[n2] = W2[t * H + (jh * 2 + n2) * 16 + jb];
  }
  float b2t = b2[t];

  // ---- prologue: ids(0), ids(1); issue gathers(0) ----
  if (tid < BLK_E) {
    int p0 = t0 * BLK_E + tid;
    if (p0 >= E) p0 = E - 1;
    unsigned pk = eidt[p0];
    eidl[0][tid] = (int)(pk & EMASK);
    bblb[0][tid] = (int)(pk >> 19);
    int p1 = (t0 + 1) * BLK_E + tid;
    if (p1 >= E) p1 = E - 1;
    pk = eidt[p1];
    eidl[1][tid] = (int)(pk & EMASK);
    bblb[1][tid] = (int)(pk >> 19);
  }
  __syncthreads();

  // row-coalesced gather: 32 lanes cover one 512B row; 2 rows/wave-load
  float4 v[8];
#pragma unroll
  for (int k = 0; k < 8; ++k) {
    int id = eidl[0][k * 16 + r0];
    v[k] = *(const float4*)(eag + (size_t)id * F + 4 * c);
  }

  // ---- cross-tile segment accumulators ----
  int wv = tid >> 6;
  int ll = tid & 63;
  float* acct = accg + (size_t)t * B * F;
  float a0 = 0.f, a1 = 0.f, asum = 0.f;
  int prev = -1;

  for (int i = 0; i < n; ++i) {
    int ib = i % 3;
    int e0 = (t0 + i) * BLK_E;

    // A: convert tile i to fp16 xh/xl (register dep on v = only vmcnt wait)
#pragma unroll
    for (int k = 0; k < 8; ++k) {
      int r = k * 16 + r0;
      float4 x = v[k];
      H4 hv, lv;
      hv.p[0] = __builtin_amdgcn_cvt_pkrtz(x.x, x.y);
      hv.p[1] = __builtin_amdgcn_cvt_pkrtz(x.z, x.w);
      lv.p[0] = __builtin_amdgcn_cvt_pkrtz(x.x - (float)hv.p[0][0],
                                           x.y - (float)hv.p[0][1]);
      lv.p[1] = __builtin_amdgcn_cvt_pkrtz(x.z - (float)hv.p[1][0],
                                           x.w - (float)hv.p[1][1]);
      int off = (r * 256 + c * 8) ^ ((r & 7) << 4);
      *(uint2*)((char*)xh_t + off) = hv.d;
      *(uint2*)((char*)xl_t + off) = lv.d;
    }
    bar_lds();  // B: tile i staged (vmcnt untouched)

    // C: early-issue ids(i+2), then gathers(i+1) — id is the OLDER vmem
    // op, so phase G's wait leaves the newer gathers outstanding.
    unsigned pk_next = 0;
    if (tid < BLK_E) {
      int p = (t0 + i + 2) * BLK_E + tid;
      if (p >= E) p = E - 1;
      pk_next = eidt[p];
    }
    if (i + 1 < n) {
      int nb = (i + 1) % 3;
#pragma unroll
      for (int k = 0; k < 8; ++k) {
        int id = eidl[nb][k * 16 + r0];
        v[k] = *(const float4*)(eag + (size_t)id * F + 4 * c);
      }
    }

    // D: MFMA — fp16 2-pass; wave covers rows rw*32..+31, j-half jh
    f32x4 acc[2][2];  // [row-subtile][nt2]
#pragma unroll
    for (int s = 0; s < 2; ++s)
#pragma unroll
      for (int n2 = 0; n2 < 2; ++n2) acc[s][n2] = (f32x4){0.f, 0.f, 0.f, 0.f};
#pragma unroll
    for (int ks = 0; ks < 4; ++ks) {
      int kb = (ks * 32 + (l >> 4) * 8) * 2;
#pragma unroll
      for (int s = 0; s < 2; ++s) {
        int arow = rw * 32 + s * 16 + (l & 15);
        int abyte = (arow * 256 + kb) ^ ((arow & 7) << 4);
        h8 ah = *(const h8*)((const char*)xh_t + abyte);
        h8 al = *(const h8*)((const char*)xl_t + abyte);
#pragma unroll
        for (int n2 = 0; n2 < 2; ++n2) {
          acc[s][n2] = __builtin_amdgcn_mfma_f32_16x16x32_f16(
              ah, bh[n2][ks], acc[s][n2], 0, 0, 0);
          acc[s][n2] = __builtin_amdgcn_mfma_f32_16x16x32_f16(
              al, bh[n2][ks], acc[s][n2], 0, 0, 0);
        }
      }
    }

    // epilogue: tanh + W2 dot over this wave's 32 j's; 16-lane reduce
#pragma unroll
    for (int s = 0; s < 2; ++s) {
      float p0 = 0.f, p1 = 0.f, p2 = 0.f, p3 = 0.f;
#pragma unroll
      for (int n2 = 0; n2 < 2; ++n2) {
        p0 = fmaf(tanh_fast(acc[s][n2][0] + b1r[n2]), w2r[n2], p0);
        p1 = fmaf(tanh_fast(acc[s][n2][1] + b1r[n2]), w2r[n2], p1);
        p2 = fmaf(tanh_fast(acc[s][n2][2] + b1r[n2]), w2r[n2], p2);
        p3 = fmaf(tanh_fast(acc[s][n2][3] + b1r[n2]), w2r[n2], p3);
      }
#pragma unroll
      for (int m = 1; m < 16; m <<= 1) {
        p0 += __shfl_xor(p0, m);
        p1 += __shfl_xor(p1, m);
        p2 += __shfl_xor(p2, m);
        p3 += __shfl_xor(p3, m);
      }
      if (jb == 0) {
        int rb = rw * 32 + s * 16 + (l >> 4) * 4;  // C/D row map (m89)
        *(float4*)&scl2[jh][rb] = (float4){p0, p1, p2, p3};
      }
    }
    bar_lds();  // E: scl2(i) ready; xh/xl still valid; vmcnt untouched

    // F: scatter; exp inline (sum of j-halves); cross-tile aggregation
    for (int ii = 0; ii < 16; ++ii) {
      int eloc = wv * 16 + ii;
      if (e0 + eloc >= E) break;  // wave-uniform (tail tiles only)
      int b = bblb[ib][eloc];     // wave-uniform
      if (b != prev) {
        if (prev >= 0) {
          atomicAdd(acct + (size_t)prev * F + 2 * ll, a0);
          atomicAdd(acct + (size_t)prev * F + 2 * ll + 1, a1);
          if (ll == 0) atomicAdd(&ssum[t * B + prev], asum);
        }
        prev = b;
        a0 = 0.f;
        a1 = 0.f;
        asum = 0.f;
      }
      float exv = __expf(scl2[0][eloc] + scl2[1][eloc] + b2t);
      int off = (eloc * 256 + ll * 4) ^ ((eloc & 7) << 4);
      h2 xh = *(const h2*)((const char*)xh_t + off);
      h2 xl = *(const h2*)((const char*)xl_t + off);
      float x0 = (float)xh[0] + (float)xl[0];
      float x1 = (float)xh[1] + (float)xl[1];
      a0 = fmaf(x0, exv, a0);
      a1 = fmaf(x1, exv, a1);
      asum += exv;
    }

    // G: commit ids(i+2); waits vmcnt only down to the id load (oldest) —
    // the newer gathers remain in flight.
    if (tid < BLK_E) {
      eidl[(i + 2) % 3][tid] = (int)(pk_next & EMASK);
      bblb[(i + 2) % 3][tid] = (int)(pk_next >> 19);
    }
    bar_lds();  // H: protects xh/xl/scl2 overwrite + id buffers
  }

  // final flush of the cross-tile segment accumulator
  if (prev >= 0) {
    atomicAdd(acct + (size_t)prev * F + 2 * ll, a0);
    atomicAdd(acct + (size_t)prev * F + 2 * ll + 1, a1);
    if (ll == 0) atomicAdd(&ssum[t * B + prev], asum);
  }
}

// ---- kernel 5: normalize + mean over types ----------------------------

__global__ __launch_bounds__(256) void k_final(
    const float* __restrict__ acc, const float* __restrict__ ssum,
    float* __restrict__ out) {
  int idx = blockIdx.x * 256 + threadIdx.x;  // b*F + f
  if (idx >= B * F) return;
  int b = idx >> 7;
  float s = 0.0f;
#pragma unroll
  for (int t = 0; t < T; ++t)
    s += acc[(size_t)t * B * F + idx] / ssum[t * B + b];
  out[idx] = s * (1.0f / 3.0f);
}

// ---- launch ------------------------------------------------------------

extern "C" void kernel_launch(void* const* d_in, const int* in_sizes, int n_in,
                              void* d_out, int out_size, void* d_ws, size_t ws_size,
                              hipStream_t stream) {
  const float* ea    = (const float*)d_in[0];
  const int*   batch = (const int*)d_in[1];
  const float* W1    = (const float*)d_in[2];
  const float* b1    = (const float*)d_in[3];
  const float* W2    = (const float*)d_in[4];
  const float* b2    = (const float*)d_in[5];
  float* out = (float*)d_out;

  // workspace: acc 1.5MB + ssum/cnt/cursor 36KB + eid 6MB + Wpack 48KB
  float*          acc    = (float*)d_ws;                  // T*B*F f32
  float*          ssum   = acc + (size_t)T * B * F;       // T*B f32
  unsigned*       cnt    = (unsigned*)(ssum + T * B);     // T*B u32
  unsigned*       cursor = cnt + T * B;                   // T*B u32
  unsigned*       eid    = cursor + T * B;                // T*E u32
  unsigned short* Wpack  = (unsigned short*)(eid + (size_t)T * E);  // 24576 u16

  k_init<<<(T * B * F + 255) / 256, 256, 0, stream>>>(W1, acc, ssum, cnt, Wpack);

  dim3 gh((E + 16383) / 16384, T);
  k_hist<<<gh, 256, 0, stream>>>(batch, cnt);
  k_scan<<<T, B, 0, stream>>>(cnt, cursor);
  dim3 ge((E + 1023) / 1024, T);
  k_scatter<<<ge, 256, 0, stream>>>(batch, cursor, eid);

  dim3 gs(PBX, T);
  k_fused<<<gs, 512, 0, stream>>>(ea, eid, Wpack, b1, W2, b2, acc, ssum);

  k_final<<<(B * F + 255) / 256, 256, 0, stream>>>(acc, ssum, out);
}

// Round 20
// 308.757 us; speedup vs baseline: 1.0017x; 1.0017x over previous
//
#include <hip/hip_runtime.h>

#define T 3
#define E 500000
#define F 128
#define H 64
#define B 1024

#define BLK_E 64
#define EMASK 0x7FFFF  // e < 2^19; graph packed in bits 19..28
#define PB 1024        // blocks per type in k_fused

typedef __attribute__((ext_vector_type(4))) float f32x4;
typedef __fp16 h2 __attribute__((ext_vector_type(2)));
typedef __fp16 h8 __attribute__((ext_vector_type(8)));
union H4 {
  h2 p[2];
  uint2 d;
};
union HS {
  __fp16 h;
  unsigned short s;
};

// ---- helpers ----------------------------------------------------------

__device__ __forceinline__ float tanh_fast(float x) {
  float e = __expf(2.0f * x);
  return 1.0f - 2.0f / (e + 1.0f);
}
// LDS-only barrier: waits DS ops, leaves VMEM counters undrained (keeps
// next-tile gathers in flight). sched_barrier fences compiler motion.
__device__ __forceinline__ void bar_lds() {
  asm volatile("s_waitcnt lgkmcnt(0)" ::: "memory");
  __builtin_amdgcn_s_barrier();
  __builtin_amdgcn_sched_barrier(0);
}

// ---- kernel 0: zero accumulators + pack W1 (fp16 RNE) into B-frags ----
// Wpack[t][nt(4)][ks(4)][lane(64)][8]: lane l holds B-frag col j =
// nt*16+(l&15), k = ks*32+(l>>4)*8 + 0..7. W-lo not needed: neglected
// x*(w-wh) term ~1e-4 in score space (validated r15/r16: absmax 9.8e-4).

__global__ void k_init(const float* __restrict__ W1, float* __restrict__ acc,
                       float* __restrict__ ssum, unsigned* __restrict__ cnt,
                       unsigned short* __restrict__ Wpack) {
  int idx = blockIdx.x * blockDim.x + threadIdx.x;
  if (idx < T * B * F) acc[idx] = 0.0f;
  if (idx < T * B) {
    ssum[idx] = 0.0f;
    cnt[idx] = 0u;
  }
  if (idx < T * 4 * 4 * 64) {
    int lane = idx & 63;
    int r2 = idx >> 6;
    int ks = r2 & 3;
    int nt = (r2 >> 2) & 3;
    int t = r2 >> 4;
    int j = nt * 16 + (lane & 15);
#pragma unroll
    for (int e = 0; e < 8; ++e) {
      int f = ks * 32 + (lane >> 4) * 8 + e;
      HS hs;
      hs.h = (__fp16)W1[((size_t)t * F + f) * H + j];  // RNE
      Wpack[(size_t)idx * 8 + e] = hs.s;
    }
  }
}

// ---- kernel 1: LDS-local histogram (16384 edges/block) ----------------

__global__ __launch_bounds__(256) void k_hist(
    const int* __restrict__ batch, unsigned* __restrict__ cnt) {
  __shared__ unsigned h[B];
  int t = blockIdx.y;
  for (int i = threadIdx.x; i < B; i += 256) h[i] = 0u;
  __syncthreads();
  int base = blockIdx.x * 16384;
  int end = base + 16384 < E ? base + 16384 : E;
  for (int i = base + threadIdx.x; i < end; i += 256)
    atomicAdd(&h[batch[(size_t)t * E + i]], 1u);
  __syncthreads();
  for (int i = threadIdx.x; i < B; i += 256) {
    unsigned v = h[i];
    if (v) atomicAdd(&cnt[t * B + i], v);
  }
}

// ---- kernel 2: prefix sums — wave-shuffle scan (2 barriers) -----------

__global__ void k_scan(const unsigned* __restrict__ cnt,
                       unsigned* __restrict__ cursor) {
  __shared__ unsigned wsum[16];
  int tid = threadIdx.x;
  int t = blockIdx.x;
  unsigned v = cnt[t * B + tid];
  unsigned x = v;  // inclusive scan within the 64-lane wave
#pragma unroll
  for (int d = 1; d < 64; d <<= 1) {
    unsigned y = __shfl_up(x, d);
    if ((tid & 63) >= d) x += y;
  }
  if ((tid & 63) == 63) wsum[tid >> 6] = x;
  __syncthreads();
  if (tid < 16) {
    unsigned s = wsum[tid];
#pragma unroll
    for (int d = 1; d < 16; d <<= 1) {
      unsigned y = __shfl_up(s, d);
      if (tid >= d) s += y;
    }
    wsum[tid] = s;
  }
  __syncthreads();
  unsigned base = (tid >> 6) ? wsum[(tid >> 6) - 1] : 0u;
  cursor[t * B + tid] = base + x - v;  // exclusive
}

// ---- kernel 3: counting-sort scatter, 1024 edges/block ----------------

__global__ __launch_bounds__(256) void k_scatter(
    const int* __restrict__ batch, unsigned* __restrict__ cursor,
    unsigned* __restrict__ eid) {
  __shared__ unsigned hloc[B];
  __shared__ unsigned baseg[B];
  int t = blockIdx.y;
  int base = blockIdx.x * 1024;
  for (int i = threadIdx.x; i < B; i += 256) hloc[i] = 0u;
  __syncthreads();
  int bb[4];
  unsigned rk[4];
#pragma unroll
  for (int k = 0; k < 4; ++k) {
    int e = base + k * 256 + threadIdx.x;
    if (e < E) {
      bb[k] = batch[(size_t)t * E + e];
      rk[k] = atomicAdd(&hloc[bb[k]], 1u);
    }
  }
  __syncthreads();
  for (int i = threadIdx.x; i < B; i += 256) {
    unsigned cv = hloc[i];
    if (cv) baseg[i] = atomicAdd(&cursor[t * B + i], cv);
  }
  __syncthreads();
#pragma unroll
  for (int k = 0; k < 4; ++k) {
    int e = base + k * 256 + threadIdx.x;
    if (e < E)
      eid[(size_t)t * E + baseg[bb[k]] + rk[k]] =
          (unsigned)e | ((unsigned)bb[k] << 19);
  }
}

// ---- kernel 4: pipelined MFMA fused score + exp + scatter -------------
// r18/r16 structure (row-coalesced gather -> register convert -> XOR-
// swizzled fp16 xh/xl LDS tiles -> LDS fragment reads -> fp16 2-pass MFMA)
// with ONE change: scatter wave wv reads only its OWN rows' scores, so the
// scl LDS round-trip + its barrier are replaced by static __shfl broadcast
// from the epilogue registers (p0..p3 hold reduced scores for rows
// w*16+(l>>4)*4+{0..3} in every lane of each 16-lane group). 2 barriers
// per tile instead of 3; no layout/occupancy/numerics change.

__global__ __launch_bounds__(256, 3) void k_fused(
    const float* __restrict__ ea, const unsigned* __restrict__ eid,
    const unsigned short* __restrict__ Wpack, const float* __restrict__ b1,
    const float* __restrict__ W2, const float* __restrict__ b2,
    float* __restrict__ accg, float* __restrict__ ssum) {
  __shared__ unsigned short xh_t[BLK_E * F];  // 16 KB fp16, row-swizzled
  __shared__ unsigned short xl_t[BLK_E * F];  // 16 KB fp16
  __shared__ int eidl[3][BLK_E];
  __shared__ int bblb[3][BLK_E];

  int t = blockIdx.y;
  int tid = threadIdx.x;
  const int NT = (E + BLK_E - 1) / BLK_E;
  const int CH = (NT + PB - 1) / PB;
  int t0 = blockIdx.x * CH;
  int n = NT - t0;
  if (n <= 0) return;
  if (n > CH) n = CH;

  const float* eag = ea + (size_t)t * E * (size_t)F;
  const unsigned* eidt = eid + (size_t)t * E;
  int l = tid & 63;
  int w = tid >> 6;
  int c = tid & 31;
  int r0 = tid >> 5;
  int jb = l & 15;

  // ---- persistent B-fragments (fp16: 64 VGPRs) + epilogue constants ----
  const unsigned short* wpt = Wpack + (size_t)t * 8192;
  h8 bh[4][4];
#pragma unroll
  for (int nt = 0; nt < 4; ++nt)
#pragma unroll
    for (int ks = 0; ks < 4; ++ks)
      bh[nt][ks] = *(const h8*)(wpt + ((nt * 4 + ks) * 64 + l) * 8);
  float b1r[4], w2r[4];
#pragma unroll
  for (int nt = 0; nt < 4; ++nt) {
    b1r[nt] = b1[t * H + nt * 16 + jb];
    w2r[nt] = W2[t * H + nt * 16 + jb];
  }
  float b2t = b2[t];

  // ---- prologue: ids(0), ids(1); issue gathers(0) ----
  if (tid < BLK_E) {
    int p0 = t0 * BLK_E + tid;
    if (p0 >= E) p0 = E - 1;
    unsigned pk = eidt[p0];
    eidl[0][tid] = (int)(pk & EMASK);
    bblb[0][tid] = (int)(pk >> 19);
    int p1 = (t0 + 1) * BLK_E + tid;
    if (p1 >= E) p1 = E - 1;
    pk = eidt[p1];
    eidl[1][tid] = (int)(pk & EMASK);
    bblb[1][tid] = (int)(pk >> 19);
  }
  __syncthreads();

  // row-coalesced gather: 32 lanes cover one 512B row; 2 rows/wave-load
  float4 v[8];
#pragma unroll
  for (int k = 0; k < 8; ++k) {
    int id = eidl[0][k * 8 + r0];
    v[k] = *(const float4*)(eag + (size_t)id * F + 4 * c);
  }

  // ---- cross-tile segment accumulators ----
  int wv = tid >> 6;
  int ll = tid & 63;
  float* acct = accg + (size_t)t * B * F;
  float a0 = 0.f, a1 = 0.f, asum = 0.f;
  int prev = -1;

  for (int i = 0; i < n; ++i) {
    int ib = i % 3;
    int e0 = (t0 + i) * BLK_E;

    // A: convert tile i to fp16 xh/xl (register dep on v = only vmcnt wait)
#pragma unroll
    for (int k = 0; k < 8; ++k) {
      int r = k * 8 + r0;
      float4 x = v[k];
      H4 hv, lv;
      hv.p[0] = __builtin_amdgcn_cvt_pkrtz(x.x, x.y);
      hv.p[1] = __builtin_amdgcn_cvt_pkrtz(x.z, x.w);
      lv.p[0] = __builtin_amdgcn_cvt_pkrtz(x.x - (float)hv.p[0][0],
                                           x.y - (float)hv.p[0][1]);
      lv.p[1] = __builtin_amdgcn_cvt_pkrtz(x.z - (float)hv.p[1][0],
                                           x.w - (float)hv.p[1][1]);
      int off = (r * 256 + c * 8) ^ ((r & 7) << 4);
      *(uint2*)((char*)xh_t + off) = hv.d;
      *(uint2*)((char*)xl_t + off) = lv.d;
    }
    bar_lds();  // B: tile i staged (vmcnt untouched)

    // C: early-issue ids(i+2), then gathers(i+1) — id is the OLDER vmem
    // op, so phase G's wait leaves the 8 newer gathers outstanding.
    unsigned pk_next = 0;
    if (tid < BLK_E) {
      int p = (t0 + i + 2) * BLK_E + tid;
      if (p >= E) p = E - 1;
      pk_next = eidt[p];
    }
    if (i + 1 < n) {
      int nb = (i + 1) % 3;
#pragma unroll
      for (int k = 0; k < 8; ++k) {
        int id = eidl[nb][k * 8 + r0];
        v[k] = *(const float4*)(eag + (size_t)id * F + 4 * c);
      }
    }

    // D: MFMA on tile i — fp16 2-pass (register B-frags + LDS A-frags)
    f32x4 acc[4];
#pragma unroll
    for (int nt = 0; nt < 4; ++nt) acc[nt] = (f32x4){0.f, 0.f, 0.f, 0.f};
    int arow = w * 16 + (l & 15);
    int abase = arow * 256;
    int aswz = (arow & 7) << 4;
#pragma unroll
    for (int ks = 0; ks < 4; ++ks) {
      int abyte = (abase + (ks * 32 + (l >> 4) * 8) * 2) ^ aswz;
      h8 ah = *(const h8*)((const char*)xh_t + abyte);
      h8 al = *(const h8*)((const char*)xl_t + abyte);
#pragma unroll
      for (int nt = 0; nt < 4; ++nt) {
        acc[nt] = __builtin_amdgcn_mfma_f32_16x16x32_f16(ah, bh[nt][ks],
                                                         acc[nt], 0, 0, 0);
        acc[nt] = __builtin_amdgcn_mfma_f32_16x16x32_f16(al, bh[nt][ks],
                                                         acc[nt], 0, 0, 0);
      }
    }

    // epilogue: tanh + W2 dot; 16-lane reduce. After the reduce every lane
    // of group g=(l>>4) holds scores of rows w*16+g*4+{0..3} in p0..p3.
    float p0 = 0.f, p1 = 0.f, p2 = 0.f, p3 = 0.f;
#pragma unroll
    for (int nt = 0; nt < 4; ++nt) {
      p0 = fmaf(tanh_fast(acc[nt][0] + b1r[nt]), w2r[nt], p0);
      p1 = fmaf(tanh_fast(acc[nt][1] + b1r[nt]), w2r[nt], p1);
      p2 = fmaf(tanh_fast(acc[nt][2] + b1r[nt]), w2r[nt], p2);
      p3 = fmaf(tanh_fast(acc[nt][3] + b1r[nt]), w2r[nt], p3);
    }
#pragma unroll
    for (int m = 1; m < 16; m <<= 1) {
      p0 += __shfl_xor(p0, m);
      p1 += __shfl_xor(p1, m);
      p2 += __shfl_xor(p2, m);
      p3 += __shfl_xor(p3, m);
    }
    // (no scl LDS write, no barrier E: scatter wave reads its OWN rows)

    // F: scatter; score via static shfl broadcast; cross-tile aggregation
#pragma unroll
    for (int ii = 0; ii < 16; ++ii) {
      int eloc = wv * 16 + ii;
      if (e0 + eloc >= E) break;  // wave-uniform (tail tiles only)
      int b = bblb[ib][eloc];     // wave-uniform
      if (b != prev) {
        if (prev >= 0) {
          atomicAdd(acct + (size_t)prev * F + 2 * ll, a0);
          atomicAdd(acct + (size_t)prev * F + 2 * ll + 1, a1);
          if (ll == 0) atomicAdd(&ssum[t * B + prev], asum);
        }
        prev = b;
        a0 = 0.f;
        a1 = 0.f;
        asum = 0.f;
      }
      // row ii's score: element ii&3 of group ii>>2 (ii is unroll-static)
      float pe = (ii & 3) == 0 ? p0
                               : ((ii & 3) == 1 ? p1 : ((ii & 3) == 2 ? p2 : p3));
      float sc = __shfl(pe, (ii >> 2) << 4);
      float exv = __expf(sc + b2t);
      int off = (eloc * 256 + ll * 4) ^ ((eloc & 7) << 4);
      h2 xh = *(const h2*)((const char*)xh_t + off);
      h2 xl = *(const h2*)((const char*)xl_t + off);
      float x0 = (float)xh[0] + (float)xl[0];
      float x1 = (float)xh[1] + (float)xl[1];
      a0 = fmaf(x0, exv, a0);
      a1 = fmaf(x1, exv, a1);
      asum += exv;
    }

    // G: commit ids(i+2); waits vmcnt only down to the id load (oldest) —
    // the 8 newer gathers remain in flight.
    if (tid < BLK_E) {
      eidl[(i + 2) % 3][tid] = (int)(pk_next & EMASK);
      bblb[(i + 2) % 3][tid] = (int)(pk_next >> 19);
    }
    bar_lds();  // H: protects xh/xl overwrite + id buffers
  }

  // final flush of the cross-tile segment accumulator
  if (prev >= 0) {
    atomicAdd(acct + (size_t)prev * F + 2 * ll, a0);
    atomicAdd(acct + (size_t)prev * F + 2 * ll + 1, a1);
    if (ll == 0) atomicAdd(&ssum[t * B + prev], asum);
  }
}

// ---- kernel 5: normalize + mean over types ----------------------------

__global__ __launch_bounds__(256) void k_final(
    const float* __restrict__ acc, const float* __restrict__ ssum,
    float* __restrict__ out) {
  int idx = blockIdx.x * 256 + threadIdx.x;  // b*F + f
  if (idx >= B * F) return;
  int b = idx >> 7;
  float s = 0.0f;
#pragma unroll
  for (int t = 0; t < T; ++t)
    s += acc[(size_t)t * B * F + idx] / ssum[t * B + b];
  out[idx] = s * (1.0f / 3.0f);
}

// ---- launch ------------------------------------------------------------

extern "C" void kernel_launch(void* const* d_in, const int* in_sizes, int n_in,
                              void* d_out, int out_size, void* d_ws, size_t ws_size,
                              hipStream_t stream) {
  const float* ea    = (const float*)d_in[0];
  const int*   batch = (const int*)d_in[1];
  const float* W1    = (const float*)d_in[2];
  const float* b1    = (const float*)d_in[3];
  const float* W2    = (const float*)d_in[4];
  const float* b2    = (const float*)d_in[5];
  float* out = (float*)d_out;

  // workspace: acc 1.5MB + ssum/cnt/cursor 36KB + eid 6MB + Wpack 48KB
  float*          acc    = (float*)d_ws;                  // T*B*F f32
  float*          ssum   = acc + (size_t)T * B * F;       // T*B f32
  unsigned*       cnt    = (unsigned*)(ssum + T * B);     // T*B u32
  unsigned*       cursor = cnt + T * B;                   // T*B u32
  unsigned*       eid    = cursor + T * B;                // T*E u32
  unsigned short* Wpack  = (unsigned short*)(eid + (size_t)T * E);  // 24576 u16

  k_init<<<(T * B * F + 255) / 256, 256, 0, stream>>>(W1, acc, ssum, cnt, Wpack);

  dim3 gh((E + 16383) / 16384, T);
  k_hist<<<gh, 256, 0, stream>>>(batch, cnt);
  k_scan<<<T, B, 0, stream>>>(cnt, cursor);
  dim3 ge((E + 1023) / 1024, T);
  k_scatter<<<ge, 256, 0, stream>>>(batch, cursor, eid);

  dim3 gs(PB, T);
  k_fused<<<gs, 256, 0, stream>>>(ea, eid, Wpack, b1, W2, b2, acc, ssum);

  k_final<<<(B * F + 255) / 256, 256, 0, stream>>>(acc, ssum, out);
}

// Round 21
// 287.912 us; speedup vs baseline: 1.0743x; 1.0724x over previous
//
#include <hip/hip_runtime.h>

#define T 3
#define E 500000
#define F 128
#define H 64
#define B 1024

#define BLK_E 64
#define EMASK 0x7FFFF  // e < 2^19; graph packed in bits 19..28
#define PB 1024        // blocks per type in k_fused

typedef __attribute__((ext_vector_type(4))) float f32x4;
typedef __fp16 h2 __attribute__((ext_vector_type(2)));
typedef __fp16 h8 __attribute__((ext_vector_type(8)));
union H4 {
  h2 p[2];
  uint2 d;
};
union HS {
  __fp16 h;
  unsigned short s;
};

// ---- helpers ----------------------------------------------------------

__device__ __forceinline__ float tanh_fast(float x) {
  float e = __expf(2.0f * x);
  return 1.0f - 2.0f / (e + 1.0f);
}
// LDS-only barrier: waits DS ops, leaves VMEM counters undrained (keeps
// next-tile gathers in flight). sched_barrier fences compiler motion.
__device__ __forceinline__ void bar_lds() {
  asm volatile("s_waitcnt lgkmcnt(0)" ::: "memory");
  __builtin_amdgcn_s_barrier();
  __builtin_amdgcn_sched_barrier(0);
}

// ---- kernel 0: zero accumulators + pack W1 (fp16 RNE) into B-frags ----
// Wpack[t][nt(4)][ks(4)][lane(64)][8]: lane l holds B-frag col j =
// nt*16+(l&15), k = ks*32+(l>>4)*8 + 0..7. W-lo not needed: neglected
// x*(w-wh) term ~1e-4 in score space (validated r15/r16: absmax 9.8e-4).

__global__ void k_init(const float* __restrict__ W1, float* __restrict__ acc,
                       float* __restrict__ ssum, unsigned* __restrict__ cnt,
                       unsigned short* __restrict__ Wpack) {
  int idx = blockIdx.x * blockDim.x + threadIdx.x;
  if (idx < T * B * F) acc[idx] = 0.0f;
  if (idx < T * B) {
    ssum[idx] = 0.0f;
    cnt[idx] = 0u;
  }
  if (idx < T * 4 * 4 * 64) {
    int lane = idx & 63;
    int r2 = idx >> 6;
    int ks = r2 & 3;
    int nt = (r2 >> 2) & 3;
    int t = r2 >> 4;
    int j = nt * 16 + (lane & 15);
#pragma unroll
    for (int e = 0; e < 8; ++e) {
      int f = ks * 32 + (lane >> 4) * 8 + e;
      HS hs;
      hs.h = (__fp16)W1[((size_t)t * F + f) * H + j];  // RNE
      Wpack[(size_t)idx * 8 + e] = hs.s;
    }
  }
}

// ---- kernel 1: LDS-local histogram (16384 edges/block) ----------------

__global__ __launch_bounds__(256) void k_hist(
    const int* __restrict__ batch, unsigned* __restrict__ cnt) {
  __shared__ unsigned h[B];
  int t = blockIdx.y;
  for (int i = threadIdx.x; i < B; i += 256) h[i] = 0u;
  __syncthreads();
  int base = blockIdx.x * 16384;
  int end = base + 16384 < E ? base + 16384 : E;
  for (int i = base + threadIdx.x; i < end; i += 256)
    atomicAdd(&h[batch[(size_t)t * E + i]], 1u);
  __syncthreads();
  for (int i = threadIdx.x; i < B; i += 256) {
    unsigned v = h[i];
    if (v) atomicAdd(&cnt[t * B + i], v);
  }
}

// ---- kernel 2: prefix sums — wave-shuffle scan (2 barriers) -----------

__global__ void k_scan(const unsigned* __restrict__ cnt,
                       unsigned* __restrict__ cursor) {
  __shared__ unsigned wsum[16];
  int tid = threadIdx.x;
  int t = blockIdx.x;
  unsigned v = cnt[t * B + tid];
  unsigned x = v;  // inclusive scan within the 64-lane wave
#pragma unroll
  for (int d = 1; d < 64; d <<= 1) {
    unsigned y = __shfl_up(x, d);
    if ((tid & 63) >= d) x += y;
  }
  if ((tid & 63) == 63) wsum[tid >> 6] = x;
  __syncthreads();
  if (tid < 16) {
    unsigned s = wsum[tid];
#pragma unroll
    for (int d = 1; d < 16; d <<= 1) {
      unsigned y = __shfl_up(s, d);
      if (tid >= d) s += y;
    }
    wsum[tid] = s;
  }
  __syncthreads();
  unsigned base = (tid >> 6) ? wsum[(tid >> 6) - 1] : 0u;
  cursor[t * B + tid] = base + x - v;  // exclusive
}

// ---- kernel 3: counting-sort scatter, 1024 edges/block ----------------

__global__ __launch_bounds__(256) void k_scatter(
    const int* __restrict__ batch, unsigned* __restrict__ cursor,
    unsigned* __restrict__ eid) {
  __shared__ unsigned hloc[B];
  __shared__ unsigned baseg[B];
  int t = blockIdx.y;
  int base = blockIdx.x * 1024;
  for (int i = threadIdx.x; i < B; i += 256) hloc[i] = 0u;
  __syncthreads();
  int bb[4];
  unsigned rk[4];
#pragma unroll
  for (int k = 0; k < 4; ++k) {
    int e = base + k * 256 + threadIdx.x;
    if (e < E) {
      bb[k] = batch[(size_t)t * E + e];
      rk[k] = atomicAdd(&hloc[bb[k]], 1u);
    }
  }
  __syncthreads();
  for (int i = threadIdx.x; i < B; i += 256) {
    unsigned cv = hloc[i];
    if (cv) baseg[i] = atomicAdd(&cursor[t * B + i], cv);
  }
  __syncthreads();
#pragma unroll
  for (int k = 0; k < 4; ++k) {
    int e = base + k * 256 + threadIdx.x;
    if (e < E)
      eid[(size_t)t * E + baseg[bb[k]] + rk[k]] =
          (unsigned)e | ((unsigned)bb[k] << 19);
  }
}

// ---- kernel 4: pipelined MFMA fused score + exp + scatter -------------
// (byte-identical to r16/r18 — empirical optimum of this structure)
// r13 skeleton (row-coalesced gather -> register convert -> XOR-swizzled
// fp16 xh/xl LDS tiles -> LDS fragment reads) + fp16 2-pass precision.

__global__ __launch_bounds__(256, 3) void k_fused(
    const float* __restrict__ ea, const unsigned* __restrict__ eid,
    const unsigned short* __restrict__ Wpack, const float* __restrict__ b1,
    const float* __restrict__ W2, const float* __restrict__ b2,
    float* __restrict__ accg, float* __restrict__ ssum) {
  __shared__ unsigned short xh_t[BLK_E * F];  // 16 KB fp16, row-swizzled
  __shared__ unsigned short xl_t[BLK_E * F];  // 16 KB fp16
  __shared__ float scl[BLK_E];
  __shared__ int eidl[3][BLK_E];
  __shared__ int bblb[3][BLK_E];

  int t = blockIdx.y;
  int tid = threadIdx.x;
  const int NT = (E + BLK_E - 1) / BLK_E;
  const int CH = (NT + PB - 1) / PB;
  int t0 = blockIdx.x * CH;
  int n = NT - t0;
  if (n <= 0) return;
  if (n > CH) n = CH;

  const float* eag = ea + (size_t)t * E * (size_t)F;
  const unsigned* eidt = eid + (size_t)t * E;
  int l = tid & 63;
  int w = tid >> 6;
  int c = tid & 31;
  int r0 = tid >> 5;
  int jb = l & 15;

  // ---- persistent B-fragments (fp16: 64 VGPRs) + epilogue constants ----
  const unsigned short* wpt = Wpack + (size_t)t * 8192;
  h8 bh[4][4];
#pragma unroll
  for (int nt = 0; nt < 4; ++nt)
#pragma unroll
    for (int ks = 0; ks < 4; ++ks)
      bh[nt][ks] = *(const h8*)(wpt + ((nt * 4 + ks) * 64 + l) * 8);
  float b1r[4], w2r[4];
#pragma unroll
  for (int nt = 0; nt < 4; ++nt) {
    b1r[nt] = b1[t * H + nt * 16 + jb];
    w2r[nt] = W2[t * H + nt * 16 + jb];
  }
  float b2t = b2[t];

  // ---- prologue: ids(0), ids(1); issue gathers(0) ----
  if (tid < BLK_E) {
    int p0 = t0 * BLK_E + tid;
    if (p0 >= E) p0 = E - 1;
    unsigned pk = eidt[p0];
    eidl[0][tid] = (int)(pk & EMASK);
    bblb[0][tid] = (int)(pk >> 19);
    int p1 = (t0 + 1) * BLK_E + tid;
    if (p1 >= E) p1 = E - 1;
    pk = eidt[p1];
    eidl[1][tid] = (int)(pk & EMASK);
    bblb[1][tid] = (int)(pk >> 19);
  }
  __syncthreads();

  // row-coalesced gather: 32 lanes cover one 512B row; 2 rows/wave-load
  float4 v[8];
#pragma unroll
  for (int k = 0; k < 8; ++k) {
    int id = eidl[0][k * 8 + r0];
    v[k] = *(const float4*)(eag + (size_t)id * F + 4 * c);
  }

  // ---- cross-tile segment accumulators ----
  int wv = tid >> 6;
  int ll = tid & 63;
  float* acct = accg + (size_t)t * B * F;
  float a0 = 0.f, a1 = 0.f, asum = 0.f;
  int prev = -1;

  for (int i = 0; i < n; ++i) {
    int ib = i % 3;
    int e0 = (t0 + i) * BLK_E;

    // A: convert tile i to fp16 xh/xl (register dep on v = only vmcnt wait)
#pragma unroll
    for (int k = 0; k < 8; ++k) {
      int r = k * 8 + r0;
      float4 x = v[k];
      H4 hv, lv;
      hv.p[0] = __builtin_amdgcn_cvt_pkrtz(x.x, x.y);
      hv.p[1] = __builtin_amdgcn_cvt_pkrtz(x.z, x.w);
      lv.p[0] = __builtin_amdgcn_cvt_pkrtz(x.x - (float)hv.p[0][0],
                                           x.y - (float)hv.p[0][1]);
      lv.p[1] = __builtin_amdgcn_cvt_pkrtz(x.z - (float)hv.p[1][0],
                                           x.w - (float)hv.p[1][1]);
      int off = (r * 256 + c * 8) ^ ((r & 7) << 4);
      *(uint2*)((char*)xh_t + off) = hv.d;
      *(uint2*)((char*)xl_t + off) = lv.d;
    }
    bar_lds();  // B: tile i staged (vmcnt untouched)

    // C: early-issue ids(i+2), then gathers(i+1) — id is the OLDER vmem
    // op, so phase G's wait leaves the 8 newer gathers outstanding.
    unsigned pk_next = 0;
    if (tid < BLK_E) {
      int p = (t0 + i + 2) * BLK_E + tid;
      if (p >= E) p = E - 1;
      pk_next = eidt[p];
    }
    if (i + 1 < n) {
      int nb = (i + 1) % 3;
#pragma unroll
      for (int k = 0; k < 8; ++k) {
        int id = eidl[nb][k * 8 + r0];
        v[k] = *(const float4*)(eag + (size_t)id * F + 4 * c);
      }
    }

    // D: MFMA on tile i — fp16 2-pass (register B-frags + LDS A-frags)
    f32x4 acc[4];
#pragma unroll
    for (int nt = 0; nt < 4; ++nt) acc[nt] = (f32x4){0.f, 0.f, 0.f, 0.f};
    int arow = w * 16 + (l & 15);
    int abase = arow * 256;
    int aswz = (arow & 7) << 4;
#pragma unroll
    for (int ks = 0; ks < 4; ++ks) {
      int abyte = (abase + (ks * 32 + (l >> 4) * 8) * 2) ^ aswz;
      h8 ah = *(const h8*)((const char*)xh_t + abyte);
      h8 al = *(const h8*)((const char*)xl_t + abyte);
#pragma unroll
      for (int nt = 0; nt < 4; ++nt) {
        acc[nt] = __builtin_amdgcn_mfma_f32_16x16x32_f16(ah, bh[nt][ks],
                                                         acc[nt], 0, 0, 0);
        acc[nt] = __builtin_amdgcn_mfma_f32_16x16x32_f16(al, bh[nt][ks],
                                                         acc[nt], 0, 0, 0);
      }
    }

    // epilogue: tanh + W2 dot; reduce over j within 16-lane groups
    float p0 = 0.f, p1 = 0.f, p2 = 0.f, p3 = 0.f;
#pragma unroll
    for (int nt = 0; nt < 4; ++nt) {
      p0 = fmaf(tanh_fast(acc[nt][0] + b1r[nt]), w2r[nt], p0);
      p1 = fmaf(tanh_fast(acc[nt][1] + b1r[nt]), w2r[nt], p1);
      p2 = fmaf(tanh_fast(acc[nt][2] + b1r[nt]), w2r[nt], p2);
      p3 = fmaf(tanh_fast(acc[nt][3] + b1r[nt]), w2r[nt], p3);
    }
#pragma unroll
    for (int m = 1; m < 16; m <<= 1) {
      p0 += __shfl_xor(p0, m);
      p1 += __shfl_xor(p1, m);
      p2 += __shfl_xor(p2, m);
      p3 += __shfl_xor(p3, m);
    }
    if (jb == 0) {
      int rb = w * 16 + (l >> 4) * 4;  // C/D row = (lane>>4)*4 + reg (m89)
      *(float4*)&scl[rb] = (float4){p0, p1, p2, p3};
    }
    bar_lds();  // E: scl(i) ready; xh/xl still valid; vmcnt untouched

    // F: scatter; exp inline from scl broadcast; cross-tile aggregation
    for (int ii = 0; ii < 16; ++ii) {
      int eloc = wv * 16 + ii;
      if (e0 + eloc >= E) break;  // wave-uniform (tail tiles only)
      int b = bblb[ib][eloc];     // wave-uniform
      if (b != prev) {
        if (prev >= 0) {
          atomicAdd(acct + (size_t)prev * F + 2 * ll, a0);
          atomicAdd(acct + (size_t)prev * F + 2 * ll + 1, a1);
          if (ll == 0) atomicAdd(&ssum[t * B + prev], asum);
        }
        prev = b;
        a0 = 0.f;
        a1 = 0.f;
        asum = 0.f;
      }
      float exv = __expf(scl[eloc] + b2t);  // LDS broadcast + trans pipe
      int off = (eloc * 256 + ll * 4) ^ ((eloc & 7) << 4);
      h2 xh = *(const h2*)((const char*)xh_t + off);
      h2 xl = *(const h2*)((const char*)xl_t + off);
      float x0 = (float)xh[0] + (float)xl[0];
      float x1 = (float)xh[1] + (float)xl[1];
      a0 = fmaf(x0, exv, a0);
      a1 = fmaf(x1, exv, a1);
      asum += exv;
    }

    // G: commit ids(i+2); waits vmcnt only down to the id load (oldest) —
    // the 8 newer gathers remain in flight.
    if (tid < BLK_E) {
      eidl[(i + 2) % 3][tid] = (int)(pk_next & EMASK);
      bblb[(i + 2) % 3][tid] = (int)(pk_next >> 19);
    }
    bar_lds();  // H: protects xh/xl/scl overwrite + id buffers
  }

  // final flush of the cross-tile segment accumulator
  if (prev >= 0) {
    atomicAdd(acct + (size_t)prev * F + 2 * ll, a0);
    atomicAdd(acct + (size_t)prev * F + 2 * ll + 1, a1);
    if (ll == 0) atomicAdd(&ssum[t * B + prev], asum);
  }
}

// ---- kernel 5: normalize + mean over types ----------------------------

__global__ __launch_bounds__(256) void k_final(
    const float* __restrict__ acc, const float* __restrict__ ssum,
    float* __restrict__ out) {
  int idx = blockIdx.x * 256 + threadIdx.x;  // b*F + f
  if (idx >= B * F) return;
  int b = idx >> 7;
  float s = 0.0f;
#pragma unroll
  for (int t = 0; t < T; ++t)
    s += acc[(size_t)t * B * F + idx] / ssum[t * B + b];
  out[idx] = s * (1.0f / 3.0f);
}

// ---- launch ------------------------------------------------------------

extern "C" void kernel_launch(void* const* d_in, const int* in_sizes, int n_in,
                              void* d_out, int out_size, void* d_ws, size_t ws_size,
                              hipStream_t stream) {
  const float* ea    = (const float*)d_in[0];
  const int*   batch = (const int*)d_in[1];
  const float* W1    = (const float*)d_in[2];
  const float* b1    = (const float*)d_in[3];
  const float* W2    = (const float*)d_in[4];
  const float* b2    = (const float*)d_in[5];
  float* out = (float*)d_out;

  // workspace: acc 1.5MB + ssum/cnt/cursor 36KB + eid 6MB + Wpack 48KB
  float*          acc    = (float*)d_ws;                  // T*B*F f32
  float*          ssum   = acc + (size_t)T * B * F;       // T*B f32
  unsigned*       cnt    = (unsigned*)(ssum + T * B);     // T*B u32
  unsigned*       cursor = cnt + T * B;                   // T*B u32
  unsigned*       eid    = cursor + T * B;                // T*E u32
  unsigned short* Wpack  = (unsigned short*)(eid + (size_t)T * E);  // 24576 u16

  k_init<<<(T * B * F + 255) / 256, 256, 0, stream>>>(W1, acc, ssum, cnt, Wpack);

  dim3 gh((E + 16383) / 16384, T);
  k_hist<<<gh, 256, 0, stream>>>(batch, cnt);
  k_scan<<<T, B, 0, stream>>>(cnt, cursor);
  dim3 ge((E + 1023) / 1024, T);
  k_scatter<<<ge, 256, 0, stream>>>(batch, cursor, eid);

  dim3 gs(PB, T);
  k_fused<<<gs, 256, 0, stream>>>(ea, eid, Wpack, b1, W2, b2, acc, ssum);

  k_final<<<(B * F + 255) / 256, 256, 0, stream>>>(acc, ssum, out);
}